// Round 1
// 190.674 us; speedup vs baseline: 1.0368x; 1.0368x over previous
//
#include <hip/hip_runtime.h>

// NGP multiresolution hash-grid interpolation encoding.
// B=262144 points, DIM=3, L=16 levels, T=19 (2^19 entries/level), F=2.
//
// R5: coarse-level LDS caching + fine-level XCD re-balance.
//  - Levels 0-2 (res 16/20/25): the full reachable sub-table is
//    (res+1)^3 entries = 39/74/141 KB -> dense-fill into LDS once per
//    8192-point block, then all 8 corner reads are ds_read_b64.
//    L2 requests for these levels: 4.7M -> ~0.52M (fill only).
//  - Levels 3-15 stay on the R4 path (paired 16B gathers), but the 13
//    levels are spread evenly across all 8 XCDs (416 of 3328 chunks each,
//    level-major) so every L2 sees an ~18.5% request reduction; removing
//    levels 0-2 from only their home XCDs would not move the makespan.
//  - 1024-thread blocks everywhere; 140.6 KB static LDS -> 1 block/CU
//    (16 waves). Fine path is L2-queue-bound (VALUBusy 10%), so the
//    occupancy drop is predicted ~free.

#define NB 262144
#define NL 16
#define TSIZE (1u << 19)
#define TMASK ((1u << 19) - 1u)
#define P1 2654435761u
#define P2 805459861u

// coarse (LDS-cached) level config
#define NCL 3                       // levels 0,1,2 cached (extents 17,21,26)
#define LDS_ENT (26 * 26 * 26)      // 17576 entries * 8B = 140608 B
#define CPTS 8192                   // points per coarse block
#define CBLKS (NB / CPTS)           // 32 blocks per coarse level
#define CB_PER_XCD ((NCL * CBLKS) / 8)        // 12
#define FINE_CHUNKS 256             // 1024-pt chunks per fine level
#define FINE_TOTAL ((NL - NCL) * FINE_CHUNKS) // 3328
#define FINE_PER_XCD (FINE_TOTAL / 8)         // 416
#define GRID_BLOCKS (8 * (CB_PER_XCD + FINE_PER_XCD))  // 3424

typedef float vf2 __attribute__((ext_vector_type(2)));
typedef float vf4 __attribute__((ext_vector_type(4)));

__constant__ float RES_C[NL] = {16.f, 20.f, 25.f, 32.f, 40.f, 50.f, 64.f, 80.f,
                                101.f, 128.f, 161.f, 203.f, 256.f, 322.f, 406.f, 512.f};

__device__ __forceinline__ void ngp_point_level(
    float px, float py, float pz, int l, const float* __restrict__ tables,
    float& o0, float& o1) {
  const float res = RES_C[l];
  const float sx = px * res, sy = py * res, sz = pz * res;
  const float fx = floorf(sx), fy = floorf(sy), fz = floorf(sz);
  const unsigned ix = (unsigned)fx, iy = (unsigned)fy, iz = (unsigned)fz;

  const unsigned hy0 = iy * P1, hy1 = hy0 + P1;
  const unsigned hz0 = iz * P2, hz1 = hz0 + P2;

  const float wx0 = 1.0f - fabsf(sx - fx);
  const float wx1 = 1.0f - fabsf(sx - (fx + 1.0f));
  const float wy0 = 1.0f - fabsf(sy - fy);
  const float wy1 = 1.0f - fabsf(sy - (fy + 1.0f));
  const float wz0 = 1.0f - fabsf(sz - fz);
  const float wz1 = 1.0f - fabsf(sz - (fz + 1.0f));

  const vf2* __restrict__ tbl2 = (const vf2*)tables + (size_t)l * TSIZE;
  const vf4* __restrict__ tbl4 = (const vf4*)tables + (size_t)l * (TSIZE / 2);

  unsigned hyz[4];
  hyz[0] = hy0 ^ hz0;
  hyz[1] = hy1 ^ hz0;
  hyz[2] = hy0 ^ hz1;
  hyz[3] = hy1 ^ hz1;

  vf2 g[8];  // g[v], v = xbit + 2*ybit + 4*zbit
  if ((ix & 1u) == 0u) {
    // even ix: x1 corner index = x0 index ^ 1 -> one aligned 16B pair.
#pragma unroll
    for (int p = 0; p < 4; ++p) {
      const unsigned i0 = (ix ^ hyz[p]) & TMASK;
      const vf4 q = tbl4[i0 >> 1];
      vf2 lo; lo.x = q.x; lo.y = q.y;
      vf2 hi; hi.x = q.z; hi.y = q.w;
      const bool x0_is_lo = (i0 & 1u) == 0u;
      g[2 * p + 0] = x0_is_lo ? lo : hi;
      g[2 * p + 1] = x0_is_lo ? hi : lo;
    }
  } else {
#pragma unroll
    for (int p = 0; p < 4; ++p) {
      const unsigned i0 = (ix ^ hyz[p]) & TMASK;
      const unsigned i1 = ((ix + 1u) ^ hyz[p]) & TMASK;
      g[2 * p + 0] = tbl2[i0];
      g[2 * p + 1] = tbl2[i1];
    }
  }

  o0 = 0.0f; o1 = 0.0f;
#pragma unroll
  for (int v = 0; v < 8; ++v) {
    const float w = ((v & 1) ? wx1 : wx0) * ((v & 2) ? wy1 : wy0) * ((v & 4) ? wz1 : wz0);
    o0 = fmaf(w, g[v].x, o0);
    o1 = fmaf(w, g[v].y, o1);
  }
}

// ---- coarse level: dense LDS sub-table fill + LDS trilinear ----
template <int E>
__device__ __forceinline__ void coarse_block(
    const int lvl, const int cchunk, const float* __restrict__ x,
    const float* __restrict__ tables, vf2* __restrict__ ws,
    vf2* __restrict__ cache) {
  const int tid = threadIdx.x;
  const vf4* __restrict__ tbl4 = (const vf4*)tables + (size_t)lvl * (TSIZE / 2);

  constexpr int HE = (E + 1) / 2;   // x-pairs per row
  constexpr int U = HE * E * E;     // fill units

  // Fill: iterate even-x pairs of the dense coord grid; hash -> one aligned
  // 16B load serves both x corners. Plain (cached) loads: footprint <1.5MB,
  // reused by all 32 blocks of this level via L2/L3.
  for (int u = tid; u < U; u += 1024) {
    const int iz = u / (HE * E);
    const int rem = u - iz * (HE * E);
    const int iy = rem / HE;
    const int ixh = rem - iy * HE;
    const unsigned ix = 2u * (unsigned)ixh;
    const unsigned h0 = (ix ^ ((unsigned)iy * P1) ^ ((unsigned)iz * P2)) & TMASK;
    const vf4 q = tbl4[h0 >> 1];
    vf2 lo; lo.x = q.x; lo.y = q.y;
    vf2 hi; hi.x = q.z; hi.y = q.w;
    const bool x0_is_lo = (h0 & 1u) == 0u;
    const int d0 = (int)ix + E * (iy + E * iz);
    cache[d0] = x0_is_lo ? lo : hi;
    if ((int)ix + 1 < E) cache[d0 + 1] = x0_is_lo ? hi : lo;
  }
  __syncthreads();

  const float res = RES_C[lvl];
  const int base = cchunk * CPTS;
#pragma unroll
  for (int k = 0; k < CPTS / 1024; ++k) {
    const int b = base + k * 1024 + tid;
    const float px = __builtin_nontemporal_load(x + b * 3 + 0);
    const float py = __builtin_nontemporal_load(x + b * 3 + 1);
    const float pz = __builtin_nontemporal_load(x + b * 3 + 2);

    const float sx = px * res, sy = py * res, sz = pz * res;
    const float fx = floorf(sx), fy = floorf(sy), fz = floorf(sz);
    const int ix = (int)fx, iy = (int)fy, iz = (int)fz;

    const float wx0 = 1.0f - fabsf(sx - fx);
    const float wx1 = 1.0f - fabsf(sx - (fx + 1.0f));
    const float wy0 = 1.0f - fabsf(sy - fy);
    const float wy1 = 1.0f - fabsf(sy - (fy + 1.0f));
    const float wz0 = 1.0f - fabsf(sz - fz);
    const float wz1 = 1.0f - fabsf(sz - (fz + 1.0f));

    const int d = ix + E * (iy + E * iz);
    vf2 g[8];
    g[0] = cache[d];
    g[1] = cache[d + 1];
    g[2] = cache[d + E];
    g[3] = cache[d + E + 1];
    g[4] = cache[d + E * E];
    g[5] = cache[d + E * E + 1];
    g[6] = cache[d + E * E + E];
    g[7] = cache[d + E * E + E + 1];

    float o0 = 0.0f, o1 = 0.0f;
#pragma unroll
    for (int v = 0; v < 8; ++v) {
      const float w = ((v & 1) ? wx1 : wx0) * ((v & 2) ? wy1 : wy0) * ((v & 4) ? wz1 : wz0);
      o0 = fmaf(w, g[v].x, o0);
      o1 = fmaf(w, g[v].y, o1);
    }
    vf2 r; r.x = o0; r.y = o1;
    __builtin_nontemporal_store(r, ws + (size_t)lvl * NB + b);
  }
}

// ---- phase 1: gather into level-major workspace ----
// bid%8 = XCD (dispatch round-robin). Per XCD: 12 coarse blocks first
// (long-running, LDS path), then 416 fine 1024-pt chunks in level-major
// order (each L2 holds ~one 4MB table at a time).
__global__ __launch_bounds__(1024) void ngp_gather_kernel(
    const float* __restrict__ x,       // (B, 3)
    const float* __restrict__ tables,  // (L, 2^19, 2)
    vf2* __restrict__ ws) {            // (L, B)
  __shared__ vf2 cache[LDS_ENT];

  const int x8 = blockIdx.x & 7;
  const int j = blockIdx.x >> 3;

  if (j < CB_PER_XCD) {
    const int u = x8 * CB_PER_XCD + j;   // 0..95
    const int lvl = u >> 5;              // /32 -> 0..2
    const int cchunk = u & 31;
    switch (lvl) {
      case 0: coarse_block<17>(0, cchunk, x, tables, ws, cache); break;
      case 1: coarse_block<21>(1, cchunk, x, tables, ws, cache); break;
      default: coarse_block<26>(2, cchunk, x, tables, ws, cache); break;
    }
    return;
  }

  const int g = x8 * FINE_PER_XCD + (j - CB_PER_XCD);  // 0..3327
  const int lvl = NCL + (g >> 8);                      // 3..15
  const int b = (g & 255) * 1024 + threadIdx.x;

  const float px = __builtin_nontemporal_load(x + b * 3 + 0);
  const float py = __builtin_nontemporal_load(x + b * 3 + 1);
  const float pz = __builtin_nontemporal_load(x + b * 3 + 2);

  float o0, o1;
  ngp_point_level(px, py, pz, lvl, tables, o0, o1);

  vf2 r; r.x = o0; r.y = o1;
  __builtin_nontemporal_store(r, ws + (size_t)lvl * NB + b);
}

// ---- phase 2: transpose ws[l][b] -> out[b][l*2+f], streaming ----
__global__ __launch_bounds__(256) void ngp_transpose_kernel(
    const vf2* __restrict__ ws,  // (L, B)
    vf4* __restrict__ out4) {    // (B, 8) float4 view of (B, 32) floats
  __shared__ vf2 tile[NL][257];
  const int t = threadIdx.x;
  const int p0 = blockIdx.x * 256;

#pragma unroll
  for (int l = 0; l < NL; ++l) {
    tile[l][t] = __builtin_nontemporal_load(ws + (size_t)l * NB + p0 + t);
  }
  __syncthreads();

#pragma unroll
  for (int k = 0; k < 8; ++k) {
    const int q = k * 256 + t;
    const int pq = q >> 3;
    const int wq = q & 7;
    const vf2 a = tile[2 * wq + 0][pq];
    const vf2 c = tile[2 * wq + 1][pq];
    vf4 v; v.x = a.x; v.y = a.y; v.z = c.x; v.w = c.y;
    __builtin_nontemporal_store(v, out4 + (size_t)p0 * 8 + q);
  }
}

// ---- fallback if workspace too small ----
__global__ __launch_bounds__(256) void ngp_fused_kernel(
    const float* __restrict__ x, const float* __restrict__ tables,
    float* __restrict__ out) {
  const int tid = blockIdx.x * blockDim.x + threadIdx.x;
  const int l = tid & (NL - 1);
  const int b = tid >> 4;
  float o0, o1;
  ngp_point_level(x[b * 3], x[b * 3 + 1], x[b * 3 + 2], l, tables, o0, o1);
  float2 r = make_float2(o0, o1);
  ((float2*)out)[tid] = r;
}

extern "C" void kernel_launch(void* const* d_in, const int* in_sizes, int n_in,
                              void* d_out, int out_size, void* d_ws, size_t ws_size,
                              hipStream_t stream) {
  const float* x = (const float*)d_in[0];
  const float* tables = (const float*)d_in[1];
  float* out = (float*)d_out;

  const size_t ws_needed = (size_t)NL * NB * sizeof(vf2);  // 32 MB
  if (ws_size >= ws_needed) {
    vf2* ws = (vf2*)d_ws;
    ngp_gather_kernel<<<GRID_BLOCKS, 1024, 0, stream>>>(x, tables, ws);
    ngp_transpose_kernel<<<NB / 256, 256, 0, stream>>>(ws, (vf4*)out);
  } else {
    ngp_fused_kernel<<<NB * NL / 256, 256, 0, stream>>>(x, tables, out);
  }
}